// Round 9
// baseline (276.090 us; speedup 1.0000x reference)
//
#include <hip/hip_runtime.h>
#include <hip/hip_bf16.h>

#define NN 50000
#define EE 800000
#define ET (NN + EE)   // edges incl. self-loops = 850000
#define SG ((NN + 255) / 256)   // scan blocks = 196
#define GB1 ((NN + 63) / 64)    // gemm1 blocks total = 782
#define GA  391                 // gemm1 blocks in launch A
#define GBB (GB1 - GA)          // gemm1 blocks in launch B = 391
#define HB  782                 // hist/scatter work blocks

typedef __attribute__((ext_vector_type(8))) short short8;
typedef __attribute__((ext_vector_type(4))) short short4b;
typedef __attribute__((ext_vector_type(4))) float f32x4;

__device__ __forceinline__ float bf2f(unsigned short u) {
    union { unsigned int i; float f; } v; v.i = ((unsigned int)u) << 16; return v.f;
}
__device__ __forceinline__ unsigned short f2bf(float f) {
    __hip_bfloat16 h = __float2bfloat16(f);
    return *reinterpret_cast<unsigned short*>(&h);
}
// lrelu(x) = max(x, 0.2x): valid for all x since 0.2x > x iff x < 0. 2 VALU ops.
__device__ __forceinline__ float lrelu(float e) { return fmaxf(e, 0.2f * e); }

// ---------------- fused single-pass scan (decoupled lookback) ----------------
// st[b] = (sum << 2) | flag; flag: 0=none, 1=aggregate, 2=inclusive. Zeroed by memset.
// All 196 blocks are co-resident (784 waves << chip capacity) -> no deadlock.
__global__ __launch_bounds__(256) void k_scan_fused(
    const int* __restrict__ cnt, int* __restrict__ st,
    int* __restrict__ rowptr, int* __restrict__ csr)
{
    int b = blockIdx.x, t = threadIdx.x, i = b * 256 + t;
    int lane = t & 63, w = t >> 6;
    int v = (i < NN) ? cnt[i] : 0;
    int s = v;
    #pragma unroll
    for (int off = 1; off < 64; off <<= 1) {
        int u = __shfl_up(s, off);
        if (lane >= off) s += u;
    }
    __shared__ int ws[4];
    __shared__ int exsh;
    if (lane == 63) ws[w] = s;
    __syncthreads();
    int a = 0;   // block total (valid on t==0)
    if (t == 0) {
        #pragma unroll
        for (int k = 0; k < 4; k++) { int x = ws[k]; ws[k] = a; a += x; }
        int flag = (b == 0) ? 2 : 1;
        __hip_atomic_store(&st[b], (a << 2) | flag, __ATOMIC_RELEASE, __HIP_MEMORY_SCOPE_AGENT);
    }
    if (w == 0 && b > 0) {   // 64-lane windowed lookback
        int ex = 0;
        int base = b - 1;
        for (;;) {
            int idx = base - lane;
            int pv = 0;
            if (idx >= 0) {
                do {
                    pv = __hip_atomic_load(&st[idx], __ATOMIC_ACQUIRE, __HIP_MEMORY_SCOPE_AGENT);
                } while ((pv & 3) == 0);
            }
            bool incl = (idx >= 0) && ((pv & 3) == 2);
            unsigned long long m = __ballot(incl);
            int contrib;
            if (m) {
                int fi = __ffsll((long long)m) - 1;   // nearest inclusive predecessor
                contrib = (idx >= 0 && lane <= fi) ? (pv >> 2) : 0;
            } else {
                contrib = (idx >= 0) ? (pv >> 2) : 0;
            }
            #pragma unroll
            for (int off = 1; off < 64; off <<= 1) contrib += __shfl_xor(contrib, off);
            ex += contrib;
            if (m) break;
            base -= 64;
        }
        if (lane == 0) {
            __hip_atomic_store(&st[b], ((a + ex) << 2) | 2, __ATOMIC_RELEASE, __HIP_MEMORY_SCOPE_AGENT);
            exsh = ex;
        }
    }
    __syncthreads();
    s += ws[w] + ((b > 0) ? exsh : 0);   // inclusive global scan of cnt
    if (i == 0) rowptr[0] = 0;
    if (i < NN) {
        int incl = s + i + 1;            // rowptr[i+1] (+i+1 = self-loops)
        rowptr[i + 1] = incl;
        int excl = incl - v - 1;         // == rowptr[i]
        csr[excl] = i;                   // self-loop first
    }
}

// ---------------- MFMA bf16 GEMM body ----------------
template<int K, int N, int NH, bool A_BF16, bool B_BF16>
__device__ __forceinline__ void gemm_body(
    int bid, const void* __restrict__ Aptr, const void* __restrict__ Wptr,
    const float* __restrict__ atts, const float* __restrict__ attd,
    unsigned short* __restrict__ C, float* __restrict__ as_, float* __restrict__ ad_,
    int M)
{
    constexpr int KU  = K / 8;        // 16B units per row
    constexpr int KUH = KU / 2;       // units per K-half
    constexpr int KC  = K / 32;       // mfma K-chunks
    constexpr int NW  = N / 4;        // cols per wave
    constexpr int NI  = NW / 16;      // 16-col tiles per wave
    constexpr int ABYTES = 64 * KU * 16;
    constexpr int BBYTES = N * KUH * 16;
    constexpr int SMEM = ABYTES + BBYTES + (NH == 1 ? 2048 : 0);
    __shared__ char smem[SMEM];
    char* Ash = smem;
    char* Bsh = smem + ABYTES;
    unsigned short* Csh = (unsigned short*)smem;          // overlay after compute
    float* scsh = (float*)(smem + ABYTES + BBYTES);       // NH==1 only

    int t = threadIdx.x;
    int lane = t & 63, w = t >> 6;
    int colL = lane & 15, quad = lane >> 4;
    int m0 = bid * 64;

    // ---- stage A (full K) ----
    {
        constexpr int CNT = 64 * KU / 256;
        #pragma unroll
        for (int i = 0; i < CNT; i++) {
            int v = t + 256 * i;
            int m = v / KU, u = v % KU;
            int gr = m0 + m; if (gr >= M) gr = M - 1;
            short8 val;
            if (A_BF16) {
                val = *(const short8*)((const unsigned short*)Aptr + (size_t)gr * K + u * 8);
            } else {
                const float* Af = (const float*)Aptr;
                float4 lo = *(const float4*)(Af + (size_t)gr * K + u * 8);
                float4 hi = *(const float4*)(Af + (size_t)gr * K + u * 8 + 4);
                val[0] = (short)f2bf(lo.x); val[1] = (short)f2bf(lo.y);
                val[2] = (short)f2bf(lo.z); val[3] = (short)f2bf(lo.w);
                val[4] = (short)f2bf(hi.x); val[5] = (short)f2bf(hi.y);
                val[6] = (short)f2bf(hi.z); val[7] = (short)f2bf(hi.w);
            }
            *(short8*)(Ash + ((size_t)m * KU + (u ^ (m & 7))) * 16) = val;
        }
    }

    f32x4 acc[4][NI];
    #pragma unroll
    for (int mi = 0; mi < 4; mi++)
        #pragma unroll
        for (int ni = 0; ni < NI; ni++) acc[mi][ni] = (f32x4){0.f, 0.f, 0.f, 0.f};

    #pragma unroll
    for (int kh = 0; kh < 2; kh++) {
        __syncthreads();
        // ---- stage B half ----
        {
            constexpr int CNT = N * KUH / 256;
            #pragma unroll
            for (int i = 0; i < CNT; i++) {
                int v = t + 256 * i;
                int n = v / KUH, uu = v % KUH;
                int u = kh * KUH + uu;
                short8 val;
                if (B_BF16) {
                    val = *(const short8*)((const unsigned short*)Wptr + (size_t)n * K + u * 8);
                } else {
                    const float* Wf = (const float*)Wptr;
                    float4 lo = *(const float4*)(Wf + (size_t)n * K + u * 8);
                    float4 hi = *(const float4*)(Wf + (size_t)n * K + u * 8 + 4);
                    val[0] = (short)f2bf(lo.x); val[1] = (short)f2bf(lo.y);
                    val[2] = (short)f2bf(lo.z); val[3] = (short)f2bf(lo.w);
                    val[4] = (short)f2bf(hi.x); val[5] = (short)f2bf(hi.y);
                    val[6] = (short)f2bf(hi.z); val[7] = (short)f2bf(hi.w);
                }
                *(short8*)(Bsh + ((size_t)n * KUH + (uu ^ (n & 7))) * 16) = val;
            }
        }
        __syncthreads();
        #pragma unroll
        for (int kcl = 0; kcl < KC / 2; kcl++) {
            int uA = (kh * (KC / 2) + kcl) * 4 + quad;
            int uB = kcl * 4 + quad;
            short8 bfr[NI];
            #pragma unroll
            for (int ni = 0; ni < NI; ni++) {
                int n = w * NW + ni * 16 + colL;
                bfr[ni] = *(const short8*)(Bsh + ((size_t)n * KUH + (uB ^ (n & 7))) * 16);
            }
            #pragma unroll
            for (int mi = 0; mi < 4; mi++) {
                int m = mi * 16 + colL;
                short8 af = *(const short8*)(Ash + ((size_t)m * KU + (uA ^ (m & 7))) * 16);
                #pragma unroll
                for (int ni = 0; ni < NI; ni++)
                    acc[mi][ni] = __builtin_amdgcn_mfma_f32_16x16x32_bf16(af, bfr[ni], acc[mi][ni], 0, 0, 0);
            }
        }
    }
    __syncthreads();   // all LDS reads done; Csh/scsh overlay safe

    // ---- attention scores ----
    float asv[NI], adv[NI];
    #pragma unroll
    for (int ni = 0; ni < NI; ni++) {
        int na = (NH == 4) ? (w * 64 + ni * 16 + colL) : (w * 16 + colL);
        asv[ni] = atts[na];
        adv[ni] = attd[na];
    }
    #pragma unroll
    for (int mi = 0; mi < 4; mi++) {
        float ps[4] = {0.f, 0.f, 0.f, 0.f}, pd[4] = {0.f, 0.f, 0.f, 0.f};
        #pragma unroll
        for (int ni = 0; ni < NI; ni++)
            #pragma unroll
            for (int r = 0; r < 4; r++) {
                ps[r] += acc[mi][ni][r] * asv[ni];
                pd[r] += acc[mi][ni][r] * adv[ni];
            }
        #pragma unroll
        for (int off = 1; off < 16; off <<= 1)
            #pragma unroll
            for (int r = 0; r < 4; r++) {
                ps[r] += __shfl_xor(ps[r], off);
                pd[r] += __shfl_xor(pd[r], off);
            }
        if (colL == 0) {
            #pragma unroll
            for (int r = 0; r < 4; r++) {
                int rloc = mi * 16 + quad * 4 + r;
                if (NH == 4) {
                    int row = m0 + rloc;
                    if (row < M) {
                        as_[(size_t)row * 4 + w] = ps[r];
                        ad_[(size_t)row * 4 + w] = pd[r];
                    }
                } else {
                    scsh[(w * 64 + rloc) * 2 + 0] = ps[r];
                    scsh[(w * 64 + rloc) * 2 + 1] = pd[r];
                }
            }
        }
    }

    // ---- C repack to LDS (bf16) ----
    #pragma unroll
    for (int mi = 0; mi < 4; mi++)
        #pragma unroll
        for (int ni = 0; ni < NI; ni++)
            #pragma unroll
            for (int r = 0; r < 4; r++)
                Csh[(size_t)(mi * 16 + quad * 4 + r) * (N + 8) + w * NW + ni * 16 + colL] =
                    f2bf(acc[mi][ni][r]);
    __syncthreads();

    // ---- coalesced global store ----
    {
        constexpr int CNT = 64 * (N / 8) / 256;
        #pragma unroll
        for (int i = 0; i < CNT; i++) {
            int v = t + 256 * i;
            int m = v / (N / 8), u = v % (N / 8);
            int row = m0 + m;
            if (row < M)
                *(short8*)(C + (size_t)row * N + u * 8) =
                    *(const short8*)(Csh + (size_t)m * (N + 8) + u * 8);
        }
    }
    if (NH == 1 && t < 64) {
        int row = m0 + t;
        if (row < M) {
            float s = 0.f, d = 0.f;
            #pragma unroll
            for (int ww = 0; ww < 4; ww++) {
                s += scsh[(ww * 64 + t) * 2 + 0];
                d += scsh[(ww * 64 + t) * 2 + 1];
            }
            as_[row] = s;
            ad_[row] = d;
        }
    }
}

// standalone GEMM (layer 2)
template<int K, int N, int NH, bool A_BF16, bool B_BF16>
__global__ __launch_bounds__(256) void k_gemm_mfma(
    const void* __restrict__ Aptr, const void* __restrict__ Wptr,
    const float* __restrict__ atts, const float* __restrict__ attd,
    unsigned short* __restrict__ C, float* __restrict__ as_, float* __restrict__ ad_,
    int M)
{
    gemm_body<K, N, NH, A_BF16, B_BF16>(blockIdx.x, Aptr, Wptr, atts, attd, C, as_, ad_, M);
}

// ---------------- launch A: gemm1 blocks 0..GA-1 striped with hist (+W2 convert) ----------------
__global__ __launch_bounds__(256) void k_gemm1_hist(
    const void* __restrict__ Aptr, const void* __restrict__ Wptr,
    const float* __restrict__ atts, const float* __restrict__ attd,
    unsigned short* __restrict__ C, float* __restrict__ as_, float* __restrict__ ad_,
    int M,
    const int* __restrict__ dst, int* __restrict__ cnt, int* __restrict__ rank,
    const float* __restrict__ W2, unsigned short* __restrict__ w2b)
{
    int bid = blockIdx.x;
    bool isg; int ord;
    if (bid < 2 * GA) { isg = !(bid & 1); ord = bid >> 1; }
    else              { isg = false;      ord = bid - GA; }
    if (isg) {
        gemm_body<128, 256, 4, false, false>(ord, Aptr, Wptr, atts, attd, C, as_, ad_, M);
    } else {
        int t = threadIdx.x;
        if (ord < 16) {   // W2 bf16 pre-convert (64*256 floats over 16 blocks)
            int j = ord * 256 + t;
            float4 v = *(const float4*)(W2 + j * 4);
            short4b o;
            o[0] = (short)f2bf(v.x); o[1] = (short)f2bf(v.y);
            o[2] = (short)f2bf(v.z); o[3] = (short)f2bf(v.w);
            *(short4b*)(w2b + j * 4) = o;
        }
        int i4 = ord * 256 + t;
        if (i4 < EE / 4) {
            int base = i4 * 4;
            int4 d = *(const int4*)(dst + base);
            int4 rr;
            rr.x = atomicAdd(&cnt[d.x], 1);
            rr.y = atomicAdd(&cnt[d.y], 1);
            rr.z = atomicAdd(&cnt[d.z], 1);
            rr.w = atomicAdd(&cnt[d.w], 1);
            *(int4*)(rank + base) = rr;
        }
    }
}

// ---------------- launch B: gemm1 blocks GA..781 striped with atomic-free scatter ----------------
__global__ __launch_bounds__(256) void k_gemm1_scatter(
    const void* __restrict__ Aptr, const void* __restrict__ Wptr,
    const float* __restrict__ atts, const float* __restrict__ attd,
    unsigned short* __restrict__ C, float* __restrict__ as_, float* __restrict__ ad_,
    int M,
    const int* __restrict__ src, const int* __restrict__ dst,
    const int* __restrict__ rank, const int* __restrict__ rowptr,
    int* __restrict__ csr)
{
    int bid = blockIdx.x;
    bool isg; int ord;
    if (bid < 2 * GBB) { isg = !(bid & 1); ord = bid >> 1; }
    else               { isg = false;      ord = bid - GBB; }
    if (isg) {
        gemm_body<128, 256, 4, false, false>(GA + ord, Aptr, Wptr, atts, attd, C, as_, ad_, M);
    } else {
        int i4 = ord * 256 + threadIdx.x;
        if (i4 < EE / 4) {
            int base = i4 * 4;
            int4 d = *(const int4*)(dst + base);
            int4 r = *(const int4*)(rank + base);
            int4 s = *(const int4*)(src + base);
            csr[rowptr[d.x] + 1 + r.x] = s.x;
            csr[rowptr[d.y] + 1 + r.y] = s.y;
            csr[rowptr[d.z] + 1 + r.z] = s.z;
            csr[rowptr[d.w] + 1 + r.w] = s.w;
        }
    }
}

// ---------------- Layer-1 aggregation: wave/node, 4 edges/half-wave in flight ----------------
__global__ __launch_bounds__(256) void k_l1_agg(
    const unsigned short* __restrict__ xt1, const float* __restrict__ as1,
    const float* __restrict__ ad1, const int* __restrict__ rowptr,
    const int* __restrict__ csr, const float* __restrict__ b1,
    unsigned short* __restrict__ h1)
{
    int t = threadIdx.x;
    int lane = t & 63, w = t >> 6;
    int n = blockIdx.x * 4 + w;
    int beg = rowptr[n], deg = rowptr[n + 1] - beg;
    int half = lane >> 5, c = lane & 31, h = c >> 3;  // lane owns channels 8c..8c+7
    float adh = ad1[n * 4 + h];
    const char* xb = (const char*)xt1;
    const char* ab = (const char*)as1;
    unsigned co = (unsigned)(c << 4);
    unsigned ho = (unsigned)(h << 2);

    float acc[8] = {0.f, 0.f, 0.f, 0.f, 0.f, 0.f, 0.f, 0.f};
    float esum = 0.f;
    int j = 0;
    for (; j + 8 <= deg; j += 8) {
        int p = beg + j + half * 4;
        int s0 = csr[p], s1 = csr[p + 1], s2 = csr[p + 2], s3 = csr[p + 3];
        float a0 = *(const float*)(ab + ((unsigned)(s0 << 4) + ho));
        float a1 = *(const float*)(ab + ((unsigned)(s1 << 4) + ho));
        float a2 = *(const float*)(ab + ((unsigned)(s2 << 4) + ho));
        float a3 = *(const float*)(ab + ((unsigned)(s3 << 4) + ho));
        short8 r0 = *(const short8*)(xb + ((unsigned)(s0 << 9) + co));
        short8 r1 = *(const short8*)(xb + ((unsigned)(s1 << 9) + co));
        short8 r2 = *(const short8*)(xb + ((unsigned)(s2 << 9) + co));
        short8 r3 = *(const short8*)(xb + ((unsigned)(s3 << 9) + co));
        float e0 = __expf(lrelu(a0 + adh));
        float e1 = __expf(lrelu(a1 + adh));
        float e2 = __expf(lrelu(a2 + adh));
        float e3 = __expf(lrelu(a3 + adh));
        esum += (e0 + e1) + (e2 + e3);
        #pragma unroll
        for (int k = 0; k < 8; k++)
            acc[k] += (bf2f((unsigned short)r0[k]) * e0 + bf2f((unsigned short)r1[k]) * e1)
                    + (bf2f((unsigned short)r2[k]) * e2 + bf2f((unsigned short)r3[k]) * e3);
    }
    if (j + 4 <= deg) {
        int p = beg + j + half * 2;
        int s0 = csr[p], s1 = csr[p + 1];
        float a0 = *(const float*)(ab + ((unsigned)(s0 << 4) + ho));
        float a1 = *(const float*)(ab + ((unsigned)(s1 << 4) + ho));
        short8 r0 = *(const short8*)(xb + ((unsigned)(s0 << 9) + co));
        short8 r1 = *(const short8*)(xb + ((unsigned)(s1 << 9) + co));
        float e0 = __expf(lrelu(a0 + adh));
        float e1 = __expf(lrelu(a1 + adh));
        esum += e0 + e1;
        #pragma unroll
        for (int k = 0; k < 8; k++)
            acc[k] += bf2f((unsigned short)r0[k]) * e0 + bf2f((unsigned short)r1[k]) * e1;
        j += 4;
    }
    for (; j < deg; j += 2) {
        int jj = j + half;
        if (jj < deg) {
            int s = csr[beg + jj];
            float a0 = *(const float*)(ab + ((unsigned)(s << 4) + ho));
            short8 r = *(const short8*)(xb + ((unsigned)(s << 9) + co));
            float e = __expf(lrelu(a0 + adh));
            esum += e;
            #pragma unroll
            for (int k = 0; k < 8; k++) acc[k] += bf2f((unsigned short)r[k]) * e;
        }
    }
    #pragma unroll
    for (int k = 0; k < 8; k++) acc[k] += __shfl_xor(acc[k], 32);
    esum += __shfl_xor(esum, 32);
    if (half == 0) {
        float rs = 1.f / (esum + 1e-16f);
        float4 bl = *(const float4*)(b1 + c * 8);
        float4 bh = *(const float4*)(b1 + c * 8 + 4);
        float bb[8] = {bl.x, bl.y, bl.z, bl.w, bh.x, bh.y, bh.z, bh.w};
        short8 o;
        #pragma unroll
        for (int k = 0; k < 8; k++)
            o[k] = (short)f2bf(fmaxf(acc[k] * rs + bb[k], 0.f));
        *(short8*)(h1 + (size_t)n * 256 + c * 8) = o;
    }
}

// ---------------- Layer-2 aggregation + fc + sigmoid: oct/edge (16B loads) ----------------
__global__ __launch_bounds__(256) void k_l2_agg(
    const unsigned short* __restrict__ xt2, const float* __restrict__ as2,
    const float* __restrict__ ad2, const int* __restrict__ rowptr,
    const int* __restrict__ csr, const float* __restrict__ b2,
    const float* __restrict__ fcw, const float* __restrict__ fcb,
    float* __restrict__ out)
{
    int t = threadIdx.x;
    int lane = t & 63, w = t >> 6;
    int n = blockIdx.x * 4 + w;
    int beg = rowptr[n], deg = rowptr[n + 1] - beg;
    int o = lane >> 3, c = lane & 7;   // 8 octs/wave; lane owns channels 8c..8c+7 (16B)
    float adv = ad2[n];
    const char* xb = (const char*)xt2;
    unsigned co = (unsigned)(c << 4);

    float acc[8] = {0.f, 0.f, 0.f, 0.f, 0.f, 0.f, 0.f, 0.f};
    float esum = 0.f;
    int j = 0;
    // main: 16 edges per wave-iter (2 per oct), depth-2 pipeline
    if (deg >= 16) {
        int p = beg + o * 2;
        int s0 = csr[p], s1 = csr[p + 1];
        float a0 = as2[s0], a1 = as2[s1];
        uint4 r0 = *(const uint4*)(xb + ((unsigned)(s0 << 7) + co));
        uint4 r1 = *(const uint4*)(xb + ((unsigned)(s1 << 7) + co));
        for (; j + 32 <= deg; j += 16) {
            int p2 = beg + j + 16 + o * 2;
            int u0 = csr[p2], u1 = csr[p2 + 1];
            float f0 = as2[u0], f1 = as2[u1];
            uint4 q0 = *(const uint4*)(xb + ((unsigned)(u0 << 7) + co));
            uint4 q1 = *(const uint4*)(xb + ((unsigned)(u1 << 7) + co));
            float e0 = __expf(lrelu(a0 + adv));
            float e1 = __expf(lrelu(a1 + adv));
            esum += e0 + e1;
            acc[0] += bf2f((unsigned short)(r0.x & 0xffff)) * e0 + bf2f((unsigned short)(r1.x & 0xffff)) * e1;
            acc[1] += bf2f((unsigned short)(r0.x >> 16))   * e0 + bf2f((unsigned short)(r1.x >> 16))   * e1;
            acc[2] += bf2f((unsigned short)(r0.y & 0xffff)) * e0 + bf2f((unsigned short)(r1.y & 0xffff)) * e1;
            acc[3] += bf2f((unsigned short)(r0.y >> 16))   * e0 + bf2f((unsigned short)(r1.y >> 16))   * e1;
            acc[4] += bf2f((unsigned short)(r0.z & 0xffff)) * e0 + bf2f((unsigned short)(r1.z & 0xffff)) * e1;
            acc[5] += bf2f((unsigned short)(r0.z >> 16))   * e0 + bf2f((unsigned short)(r1.z >> 16))   * e1;
            acc[6] += bf2f((unsigned short)(r0.w & 0xffff)) * e0 + bf2f((unsigned short)(r1.w & 0xffff)) * e1;
            acc[7] += bf2f((unsigned short)(r0.w >> 16))   * e0 + bf2f((unsigned short)(r1.w >> 16))   * e1;
            a0 = f0; a1 = f1; r0 = q0; r1 = q1;
        }
        {   // drain last loaded group
            float e0 = __expf(lrelu(a0 + adv));
            float e1 = __expf(lrelu(a1 + adv));
            esum += e0 + e1;
            acc[0] += bf2f((unsigned short)(r0.x & 0xffff)) * e0 + bf2f((unsigned short)(r1.x & 0xffff)) * e1;
            acc[1] += bf2f((unsigned short)(r0.x >> 16))   * e0 + bf2f((unsigned short)(r1.x >> 16))   * e1;
            acc[2] += bf2f((unsigned short)(r0.y & 0xffff)) * e0 + bf2f((unsigned short)(r1.y & 0xffff)) * e1;
            acc[3] += bf2f((unsigned short)(r0.y >> 16))   * e0 + bf2f((unsigned short)(r1.y >> 16))   * e1;
            acc[4] += bf2f((unsigned short)(r0.z & 0xffff)) * e0 + bf2f((unsigned short)(r1.z & 0xffff)) * e1;
            acc[5] += bf2f((unsigned short)(r0.z >> 16))   * e0 + bf2f((unsigned short)(r1.z >> 16))   * e1;
            acc[6] += bf2f((unsigned short)(r0.w & 0xffff)) * e0 + bf2f((unsigned short)(r1.w & 0xffff)) * e1;
            acc[7] += bf2f((unsigned short)(r0.w >> 16))   * e0 + bf2f((unsigned short)(r1.w >> 16))   * e1;
            j += 16;
        }
    }
    // mid: 8 edges (1 per oct)
    if (j + 8 <= deg) {
        int s0 = csr[beg + j + o];
        float a0 = as2[s0];
        uint4 r0 = *(const uint4*)(xb + ((unsigned)(s0 << 7) + co));
        float e0 = __expf(lrelu(a0 + adv));
        esum += e0;
        acc[0] += bf2f((unsigned short)(r0.x & 0xffff)) * e0;
        acc[1] += bf2f((unsigned short)(r0.x >> 16))   * e0;
        acc[2] += bf2f((unsigned short)(r0.y & 0xffff)) * e0;
        acc[3] += bf2f((unsigned short)(r0.y >> 16))   * e0;
        acc[4] += bf2f((unsigned short)(r0.z & 0xffff)) * e0;
        acc[5] += bf2f((unsigned short)(r0.z >> 16))   * e0;
        acc[6] += bf2f((unsigned short)(r0.w & 0xffff)) * e0;
        acc[7] += bf2f((unsigned short)(r0.w >> 16))   * e0;
        j += 8;
    }
    // tail: < 8 edges, one pass (oct o handles edge j+o)
    {
        int jj = j + o;
        if (jj < deg) {
            int s0 = csr[beg + jj];
            float a0 = as2[s0];
            uint4 r0 = *(const uint4*)(xb + ((unsigned)(s0 << 7) + co));
            float e0 = __expf(lrelu(a0 + adv));
            esum += e0;
            acc[0] += bf2f((unsigned short)(r0.x & 0xffff)) * e0;
            acc[1] += bf2f((unsigned short)(r0.x >> 16))   * e0;
            acc[2] += bf2f((unsigned short)(r0.y & 0xffff)) * e0;
            acc[3] += bf2f((unsigned short)(r0.y >> 16))   * e0;
            acc[4] += bf2f((unsigned short)(r0.z & 0xffff)) * e0;
            acc[5] += bf2f((unsigned short)(r0.z >> 16))   * e0;
            acc[6] += bf2f((unsigned short)(r0.w & 0xffff)) * e0;
            acc[7] += bf2f((unsigned short)(r0.w >> 16))   * e0;
        }
    }
    #pragma unroll
    for (int k = 0; k < 8; k++) {
        acc[k] += __shfl_xor(acc[k], 8);
        acc[k] += __shfl_xor(acc[k], 16);
        acc[k] += __shfl_xor(acc[k], 32);
    }
    esum += __shfl_xor(esum, 8);
    esum += __shfl_xor(esum, 16);
    esum += __shfl_xor(esum, 32);
    float rs = 1.f / (esum + 1e-16f);
    float4 b0 = *(const float4*)(b2 + c * 8);
    float4 b1v = *(const float4*)(b2 + c * 8 + 4);
    float4 f0v = *(const float4*)(fcw + c * 8);
    float4 f1v = *(const float4*)(fcw + c * 8 + 4);
    float z = fmaxf(acc[0] * rs + b0.x, 0.f) * f0v.x
            + fmaxf(acc[1] * rs + b0.y, 0.f) * f0v.y
            + fmaxf(acc[2] * rs + b0.z, 0.f) * f0v.z
            + fmaxf(acc[3] * rs + b0.w, 0.f) * f0v.w
            + fmaxf(acc[4] * rs + b1v.x, 0.f) * f1v.x
            + fmaxf(acc[5] * rs + b1v.y, 0.f) * f1v.y
            + fmaxf(acc[6] * rs + b1v.z, 0.f) * f1v.z
            + fmaxf(acc[7] * rs + b1v.w, 0.f) * f1v.w;
    z += __shfl_xor(z, 1);
    z += __shfl_xor(z, 2);
    z += __shfl_xor(z, 4);
    if (lane == 0) out[n] = 1.f / (1.f + __expf(-(z + fcb[0])));
}

// ---------------- launch ----------------

extern "C" void kernel_launch(void* const* d_in, const int* in_sizes, int n_in,
                              void* d_out, int out_size, void* d_ws, size_t ws_size,
                              hipStream_t stream) {
    const float* x    = (const float*)d_in[0];
    const int*   ei   = (const int*)d_in[1];
    const float* W1   = (const float*)d_in[2];
    const float* as1w = (const float*)d_in[3];
    const float* ad1w = (const float*)d_in[4];
    const float* b1   = (const float*)d_in[5];
    const float* W2   = (const float*)d_in[6];
    const float* as2w = (const float*)d_in[7];
    const float* ad2w = (const float*)d_in[8];
    const float* b2   = (const float*)d_in[9];
    const float* fcw  = (const float*)d_in[10];
    const float* fcb  = (const float*)d_in[11];
    float* out = (float*)d_out;

    const int* src = ei;
    const int* dst = ei + EE;

    char* base = (char*)d_ws;
    size_t off = 0;
    auto alloc = [&](size_t bytes) -> void* {
        void* p = base + off;
        off = (off + bytes + 255) & ~(size_t)255;
        return p;
    };
    int*   rowptr   = (int*)alloc((NN + 1) * sizeof(int));
    int*   cnt      = (int*)alloc((NN + SG) * sizeof(int));   // cnt + lookback state
    int*   st       = cnt + NN;
    int*   rank     = (int*)alloc(EE * sizeof(int));
    int*   csr      = (int*)alloc(ET * sizeof(int));
    unsigned short* xt1 = (unsigned short*)alloc((size_t)NN * 256 * sizeof(unsigned short));
    unsigned short* h1  = (unsigned short*)alloc((size_t)NN * 256 * sizeof(unsigned short));
    unsigned short* w2b = (unsigned short*)alloc(64 * 256 * sizeof(unsigned short));
    float* as1      = (float*)alloc(NN * 4 * sizeof(float));
    float* ad1      = (float*)alloc(NN * 4 * sizeof(float));
    float* as2      = (float*)alloc(NN * sizeof(float));
    float* ad2      = (float*)alloc(NN * sizeof(float));
    unsigned short* xt2 = xt1;   // xt1 dead after l1_agg; reuse

    hipMemsetAsync(cnt, 0, (NN + SG) * sizeof(int), stream);   // cnt + st

    // launch A: first half of gemm1 striped with hist (+W2 convert, rank capture)
    k_gemm1_hist<<<2 * GA + (HB - GA), 256, 0, stream>>>(
        x, W1, as1w, ad1w, xt1, as1, ad1, NN, dst, cnt, rank, W2, w2b);

    // single-pass scan (rowptr + csr self-loops)
    k_scan_fused<<<SG, 256, 0, stream>>>(cnt, st, rowptr, csr);

    // launch B: second half of gemm1 striped with atomic-free scatter
    k_gemm1_scatter<<<2 * GBB + (HB - GBB), 256, 0, stream>>>(
        x, W1, as1w, ad1w, xt1, as1, ad1, NN, src, dst, rank, rowptr, csr);

    k_l1_agg<<<(NN + 3) / 4, 256, 0, stream>>>(xt1, as1, ad1, rowptr, csr, b1, h1);
    k_gemm_mfma<256, 64, 1, true, true><<<GB1, 256, 0, stream>>>(
        h1, w2b, as2w, ad2w, xt2, as2, ad2, NN);
    k_l2_agg<<<(NN + 3) / 4, 256, 0, stream>>>(xt2, as2, ad2, rowptr, csr, b2, fcw, fcb, out);
}

// Round 10
// 266.181 us; speedup vs baseline: 1.0372x; 1.0372x over previous
//
#include <hip/hip_runtime.h>
#include <hip/hip_bf16.h>

#define NN 50000
#define EE 800000
#define ET (NN + EE)   // edges incl. self-loops = 850000
#define SG ((NN + 255) / 256)   // scan blocks = 196
#define GB1 ((NN + 63) / 64)    // gemm1 blocks total = 782
#define GA  391                 // gemm1 blocks in launch A
#define GBB (GB1 - GA)          // gemm1 blocks in launch B = 391
#define HB  782                 // hist/scatter work blocks

typedef __attribute__((ext_vector_type(8))) short short8;
typedef __attribute__((ext_vector_type(4))) short short4b;
typedef __attribute__((ext_vector_type(4))) float f32x4;

__device__ __forceinline__ float bf2f(unsigned short u) {
    union { unsigned int i; float f; } v; v.i = ((unsigned int)u) << 16; return v.f;
}
__device__ __forceinline__ unsigned short f2bf(float f) {
    __hip_bfloat16 h = __float2bfloat16(f);
    return *reinterpret_cast<unsigned short*>(&h);
}
// lrelu(x) = max(x, 0.2x): valid for all x since 0.2x > x iff x < 0. 2 VALU ops.
__device__ __forceinline__ float lrelu(float e) { return fmaxf(e, 0.2f * e); }

// ---------------- scans (3-kernel chain; lookback variant regressed in R9) ----------------

__global__ __launch_bounds__(256) void k_scan1(const int* __restrict__ cnt,
                                               int* __restrict__ tmp, int* __restrict__ bsum) {
    int b = blockIdx.x, t = threadIdx.x, i = b * 256 + t;
    int lane = t & 63, w = t >> 6;
    int v = (i < NN) ? cnt[i] : 0;
    int s = v;
    #pragma unroll
    for (int off = 1; off < 64; off <<= 1) {
        int u = __shfl_up(s, off);
        if (lane >= off) s += u;
    }
    __shared__ int ws[4];
    if (lane == 63) ws[w] = s;
    __syncthreads();
    if (t == 0) {
        int a = 0;
        #pragma unroll
        for (int k = 0; k < 4; k++) { int x = ws[k]; ws[k] = a; a += x; }
        bsum[b] = a;
    }
    __syncthreads();
    s += ws[w];
    if (i < NN) tmp[i] = s;   // inclusive within block (edge counts only)
}

__global__ __launch_bounds__(256) void k_scan2(const int* __restrict__ bsum, int* __restrict__ boff) {
    int t = threadIdx.x, lane = t & 63, w = t >> 6;
    int v = (t < SG) ? bsum[t] : 0;
    int s = v;
    #pragma unroll
    for (int off = 1; off < 64; off <<= 1) {
        int u = __shfl_up(s, off);
        if (lane >= off) s += u;
    }
    __shared__ int ws[4];
    if (lane == 63) ws[w] = s;
    __syncthreads();
    if (t == 0) {
        int a = 0;
        #pragma unroll
        for (int k = 0; k < 4; k++) { int x = ws[k]; ws[k] = a; a += x; }
    }
    __syncthreads();
    s += ws[w];
    if (t < SG) boff[t] = s - v;   // exclusive
}

__global__ void k_scan3_prep(const int* __restrict__ tmp, const int* __restrict__ boff,
                             int* __restrict__ rowptr, int* __restrict__ csr) {
    int i = blockIdx.x * blockDim.x + threadIdx.x;
    if (i == 0) rowptr[0] = 0;
    if (i < NN) {
        int base = boff[i >> 8];
        int incl = tmp[i] + base + i + 1;
        rowptr[i + 1] = incl;
        int excl = ((i & 255) ? tmp[i - 1] + base : base) + i;   // == rowptr[i]
        csr[excl] = i;            // self-loop first
    }
}

// ---------------- MFMA bf16 GEMM body ----------------
template<int K, int N, int NH, bool A_BF16, bool B_BF16>
__device__ __forceinline__ void gemm_body(
    int bid, const void* __restrict__ Aptr, const void* __restrict__ Wptr,
    const float* __restrict__ atts, const float* __restrict__ attd,
    unsigned short* __restrict__ C, float* __restrict__ as_, float* __restrict__ ad_,
    int M)
{
    constexpr int KU  = K / 8;        // 16B units per row
    constexpr int KUH = KU / 2;       // units per K-half
    constexpr int KC  = K / 32;       // mfma K-chunks
    constexpr int NW  = N / 4;        // cols per wave
    constexpr int NI  = NW / 16;      // 16-col tiles per wave
    constexpr int ABYTES = 64 * KU * 16;
    constexpr int BBYTES = N * KUH * 16;
    constexpr int SMEM = ABYTES + BBYTES + (NH == 1 ? 2048 : 0);
    __shared__ char smem[SMEM];
    char* Ash = smem;
    char* Bsh = smem + ABYTES;
    unsigned short* Csh = (unsigned short*)smem;          // overlay after compute
    float* scsh = (float*)(smem + ABYTES + BBYTES);       // NH==1 only

    int t = threadIdx.x;
    int lane = t & 63, w = t >> 6;
    int colL = lane & 15, quad = lane >> 4;
    int m0 = bid * 64;

    // ---- stage A (full K) ----
    {
        constexpr int CNT = 64 * KU / 256;
        #pragma unroll
        for (int i = 0; i < CNT; i++) {
            int v = t + 256 * i;
            int m = v / KU, u = v % KU;
            int gr = m0 + m; if (gr >= M) gr = M - 1;
            short8 val;
            if (A_BF16) {
                val = *(const short8*)((const unsigned short*)Aptr + (size_t)gr * K + u * 8);
            } else {
                const float* Af = (const float*)Aptr;
                float4 lo = *(const float4*)(Af + (size_t)gr * K + u * 8);
                float4 hi = *(const float4*)(Af + (size_t)gr * K + u * 8 + 4);
                val[0] = (short)f2bf(lo.x); val[1] = (short)f2bf(lo.y);
                val[2] = (short)f2bf(lo.z); val[3] = (short)f2bf(lo.w);
                val[4] = (short)f2bf(hi.x); val[5] = (short)f2bf(hi.y);
                val[6] = (short)f2bf(hi.z); val[7] = (short)f2bf(hi.w);
            }
            *(short8*)(Ash + ((size_t)m * KU + (u ^ (m & 7))) * 16) = val;
        }
    }

    f32x4 acc[4][NI];
    #pragma unroll
    for (int mi = 0; mi < 4; mi++)
        #pragma unroll
        for (int ni = 0; ni < NI; ni++) acc[mi][ni] = (f32x4){0.f, 0.f, 0.f, 0.f};

    #pragma unroll
    for (int kh = 0; kh < 2; kh++) {
        __syncthreads();
        // ---- stage B half ----
        {
            constexpr int CNT = N * KUH / 256;
            #pragma unroll
            for (int i = 0; i < CNT; i++) {
                int v = t + 256 * i;
                int n = v / KUH, uu = v % KUH;
                int u = kh * KUH + uu;
                short8 val;
                if (B_BF16) {
                    val = *(const short8*)((const unsigned short*)Wptr + (size_t)n * K + u * 8);
                } else {
                    const float* Wf = (const float*)Wptr;
                    float4 lo = *(const float4*)(Wf + (size_t)n * K + u * 8);
                    float4 hi = *(const float4*)(Wf + (size_t)n * K + u * 8 + 4);
                    val[0] = (short)f2bf(lo.x); val[1] = (short)f2bf(lo.y);
                    val[2] = (short)f2bf(lo.z); val[3] = (short)f2bf(lo.w);
                    val[4] = (short)f2bf(hi.x); val[5] = (short)f2bf(hi.y);
                    val[6] = (short)f2bf(hi.z); val[7] = (short)f2bf(hi.w);
                }
                *(short8*)(Bsh + ((size_t)n * KUH + (uu ^ (n & 7))) * 16) = val;
            }
        }
        __syncthreads();
        #pragma unroll
        for (int kcl = 0; kcl < KC / 2; kcl++) {
            int uA = (kh * (KC / 2) + kcl) * 4 + quad;
            int uB = kcl * 4 + quad;
            short8 bfr[NI];
            #pragma unroll
            for (int ni = 0; ni < NI; ni++) {
                int n = w * NW + ni * 16 + colL;
                bfr[ni] = *(const short8*)(Bsh + ((size_t)n * KUH + (uB ^ (n & 7))) * 16);
            }
            #pragma unroll
            for (int mi = 0; mi < 4; mi++) {
                int m = mi * 16 + colL;
                short8 af = *(const short8*)(Ash + ((size_t)m * KU + (uA ^ (m & 7))) * 16);
                #pragma unroll
                for (int ni = 0; ni < NI; ni++)
                    acc[mi][ni] = __builtin_amdgcn_mfma_f32_16x16x32_bf16(af, bfr[ni], acc[mi][ni], 0, 0, 0);
            }
        }
    }
    __syncthreads();   // all LDS reads done; Csh/scsh overlay safe

    // ---- attention scores ----
    float asv[NI], adv[NI];
    #pragma unroll
    for (int ni = 0; ni < NI; ni++) {
        int na = (NH == 4) ? (w * 64 + ni * 16 + colL) : (w * 16 + colL);
        asv[ni] = atts[na];
        adv[ni] = attd[na];
    }
    #pragma unroll
    for (int mi = 0; mi < 4; mi++) {
        float ps[4] = {0.f, 0.f, 0.f, 0.f}, pd[4] = {0.f, 0.f, 0.f, 0.f};
        #pragma unroll
        for (int ni = 0; ni < NI; ni++)
            #pragma unroll
            for (int r = 0; r < 4; r++) {
                ps[r] += acc[mi][ni][r] * asv[ni];
                pd[r] += acc[mi][ni][r] * adv[ni];
            }
        #pragma unroll
        for (int off = 1; off < 16; off <<= 1)
            #pragma unroll
            for (int r = 0; r < 4; r++) {
                ps[r] += __shfl_xor(ps[r], off);
                pd[r] += __shfl_xor(pd[r], off);
            }
        if (colL == 0) {
            #pragma unroll
            for (int r = 0; r < 4; r++) {
                int rloc = mi * 16 + quad * 4 + r;
                if (NH == 4) {
                    int row = m0 + rloc;
                    if (row < M) {
                        as_[(size_t)row * 4 + w] = ps[r];
                        ad_[(size_t)row * 4 + w] = pd[r];
                    }
                } else {
                    scsh[(w * 64 + rloc) * 2 + 0] = ps[r];
                    scsh[(w * 64 + rloc) * 2 + 1] = pd[r];
                }
            }
        }
    }

    // ---- C repack to LDS (bf16) ----
    #pragma unroll
    for (int mi = 0; mi < 4; mi++)
        #pragma unroll
        for (int ni = 0; ni < NI; ni++)
            #pragma unroll
            for (int r = 0; r < 4; r++)
                Csh[(size_t)(mi * 16 + quad * 4 + r) * (N + 8) + w * NW + ni * 16 + colL] =
                    f2bf(acc[mi][ni][r]);
    __syncthreads();

    // ---- coalesced global store ----
    {
        constexpr int CNT = 64 * (N / 8) / 256;
        #pragma unroll
        for (int i = 0; i < CNT; i++) {
            int v = t + 256 * i;
            int m = v / (N / 8), u = v % (N / 8);
            int row = m0 + m;
            if (row < M)
                *(short8*)(C + (size_t)row * N + u * 8) =
                    *(const short8*)(Csh + (size_t)m * (N + 8) + u * 8);
        }
    }
    if (NH == 1 && t < 64) {
        int row = m0 + t;
        if (row < M) {
            float s = 0.f, d = 0.f;
            #pragma unroll
            for (int ww = 0; ww < 4; ww++) {
                s += scsh[(ww * 64 + t) * 2 + 0];
                d += scsh[(ww * 64 + t) * 2 + 1];
            }
            as_[row] = s;
            ad_[row] = d;
        }
    }
}

// standalone GEMM (layer 2)
template<int K, int N, int NH, bool A_BF16, bool B_BF16>
__global__ __launch_bounds__(256) void k_gemm_mfma(
    const void* __restrict__ Aptr, const void* __restrict__ Wptr,
    const float* __restrict__ atts, const float* __restrict__ attd,
    unsigned short* __restrict__ C, float* __restrict__ as_, float* __restrict__ ad_,
    int M)
{
    gemm_body<K, N, NH, A_BF16, B_BF16>(blockIdx.x, Aptr, Wptr, atts, attd, C, as_, ad_, M);
}

// ---------------- launch A: gemm1 blocks 0..GA-1 striped with hist (+W2 convert) ----------------
__global__ __launch_bounds__(256) void k_gemm1_hist(
    const void* __restrict__ Aptr, const void* __restrict__ Wptr,
    const float* __restrict__ atts, const float* __restrict__ attd,
    unsigned short* __restrict__ C, float* __restrict__ as_, float* __restrict__ ad_,
    int M,
    const int* __restrict__ dst, int* __restrict__ cnt, int* __restrict__ rank,
    const float* __restrict__ W2, unsigned short* __restrict__ w2b)
{
    int bid = blockIdx.x;
    bool isg; int ord;
    if (bid < 2 * GA) { isg = !(bid & 1); ord = bid >> 1; }
    else              { isg = false;      ord = bid - GA; }
    if (isg) {
        gemm_body<128, 256, 4, false, false>(ord, Aptr, Wptr, atts, attd, C, as_, ad_, M);
    } else {
        int t = threadIdx.x;
        if (ord < 16) {   // W2 bf16 pre-convert (64*256 floats over 16 blocks)
            int j = ord * 256 + t;
            float4 v = *(const float4*)(W2 + j * 4);
            short4b o;
            o[0] = (short)f2bf(v.x); o[1] = (short)f2bf(v.y);
            o[2] = (short)f2bf(v.z); o[3] = (short)f2bf(v.w);
            *(short4b*)(w2b + j * 4) = o;
        }
        int i4 = ord * 256 + t;
        if (i4 < EE / 4) {
            int base = i4 * 4;
            int4 d = *(const int4*)(dst + base);
            int4 rr;
            rr.x = atomicAdd(&cnt[d.x], 1);
            rr.y = atomicAdd(&cnt[d.y], 1);
            rr.z = atomicAdd(&cnt[d.z], 1);
            rr.w = atomicAdd(&cnt[d.w], 1);
            *(int4*)(rank + base) = rr;
        }
    }
}

// ---------------- launch B: gemm1 blocks GA..781 striped with atomic-free scatter ----------------
__global__ __launch_bounds__(256) void k_gemm1_scatter(
    const void* __restrict__ Aptr, const void* __restrict__ Wptr,
    const float* __restrict__ atts, const float* __restrict__ attd,
    unsigned short* __restrict__ C, float* __restrict__ as_, float* __restrict__ ad_,
    int M,
    const int* __restrict__ src, const int* __restrict__ dst,
    const int* __restrict__ rank, const int* __restrict__ rowptr,
    int* __restrict__ csr)
{
    int bid = blockIdx.x;
    bool isg; int ord;
    if (bid < 2 * GBB) { isg = !(bid & 1); ord = bid >> 1; }
    else               { isg = false;      ord = bid - GBB; }
    if (isg) {
        gemm_body<128, 256, 4, false, false>(GA + ord, Aptr, Wptr, atts, attd, C, as_, ad_, M);
    } else {
        int i4 = ord * 256 + threadIdx.x;
        if (i4 < EE / 4) {
            int base = i4 * 4;
            int4 d = *(const int4*)(dst + base);
            int4 r = *(const int4*)(rank + base);
            int4 s = *(const int4*)(src + base);
            csr[rowptr[d.x] + 1 + r.x] = s.x;
            csr[rowptr[d.y] + 1 + r.y] = s.y;
            csr[rowptr[d.z] + 1 + r.z] = s.z;
            csr[rowptr[d.w] + 1 + r.w] = s.w;
        }
    }
}

// ---------------- Layer-1 aggregation: wave/node, 4 edges/half-wave in flight ----------------
__global__ __launch_bounds__(256) void k_l1_agg(
    const unsigned short* __restrict__ xt1, const float* __restrict__ as1,
    const float* __restrict__ ad1, const int* __restrict__ rowptr,
    const int* __restrict__ csr, const float* __restrict__ b1,
    unsigned short* __restrict__ h1)
{
    int t = threadIdx.x;
    int lane = t & 63, w = t >> 6;
    int n = blockIdx.x * 4 + w;
    int beg = rowptr[n], deg = rowptr[n + 1] - beg;
    int half = lane >> 5, c = lane & 31, h = c >> 3;  // lane owns channels 8c..8c+7
    float adh = ad1[n * 4 + h];
    const char* xb = (const char*)xt1;
    const char* ab = (const char*)as1;
    unsigned co = (unsigned)(c << 4);
    unsigned ho = (unsigned)(h << 2);

    float acc[8] = {0.f, 0.f, 0.f, 0.f, 0.f, 0.f, 0.f, 0.f};
    float esum = 0.f;
    int j = 0;
    for (; j + 8 <= deg; j += 8) {
        int p = beg + j + half * 4;
        int s0 = csr[p], s1 = csr[p + 1], s2 = csr[p + 2], s3 = csr[p + 3];
        float a0 = *(const float*)(ab + ((unsigned)(s0 << 4) + ho));
        float a1 = *(const float*)(ab + ((unsigned)(s1 << 4) + ho));
        float a2 = *(const float*)(ab + ((unsigned)(s2 << 4) + ho));
        float a3 = *(const float*)(ab + ((unsigned)(s3 << 4) + ho));
        short8 r0 = *(const short8*)(xb + ((unsigned)(s0 << 9) + co));
        short8 r1 = *(const short8*)(xb + ((unsigned)(s1 << 9) + co));
        short8 r2 = *(const short8*)(xb + ((unsigned)(s2 << 9) + co));
        short8 r3 = *(const short8*)(xb + ((unsigned)(s3 << 9) + co));
        float e0 = __expf(lrelu(a0 + adh));
        float e1 = __expf(lrelu(a1 + adh));
        float e2 = __expf(lrelu(a2 + adh));
        float e3 = __expf(lrelu(a3 + adh));
        esum += (e0 + e1) + (e2 + e3);
        #pragma unroll
        for (int k = 0; k < 8; k++)
            acc[k] += (bf2f((unsigned short)r0[k]) * e0 + bf2f((unsigned short)r1[k]) * e1)
                    + (bf2f((unsigned short)r2[k]) * e2 + bf2f((unsigned short)r3[k]) * e3);
    }
    if (j + 4 <= deg) {
        int p = beg + j + half * 2;
        int s0 = csr[p], s1 = csr[p + 1];
        float a0 = *(const float*)(ab + ((unsigned)(s0 << 4) + ho));
        float a1 = *(const float*)(ab + ((unsigned)(s1 << 4) + ho));
        short8 r0 = *(const short8*)(xb + ((unsigned)(s0 << 9) + co));
        short8 r1 = *(const short8*)(xb + ((unsigned)(s1 << 9) + co));
        float e0 = __expf(lrelu(a0 + adh));
        float e1 = __expf(lrelu(a1 + adh));
        esum += e0 + e1;
        #pragma unroll
        for (int k = 0; k < 8; k++)
            acc[k] += bf2f((unsigned short)r0[k]) * e0 + bf2f((unsigned short)r1[k]) * e1;
        j += 4;
    }
    for (; j < deg; j += 2) {
        int jj = j + half;
        if (jj < deg) {
            int s = csr[beg + jj];
            float a0 = *(const float*)(ab + ((unsigned)(s << 4) + ho));
            short8 r = *(const short8*)(xb + ((unsigned)(s << 9) + co));
            float e = __expf(lrelu(a0 + adh));
            esum += e;
            #pragma unroll
            for (int k = 0; k < 8; k++) acc[k] += bf2f((unsigned short)r[k]) * e;
        }
    }
    #pragma unroll
    for (int k = 0; k < 8; k++) acc[k] += __shfl_xor(acc[k], 32);
    esum += __shfl_xor(esum, 32);
    if (half == 0) {
        float rs = 1.f / (esum + 1e-16f);
        float4 bl = *(const float4*)(b1 + c * 8);
        float4 bh = *(const float4*)(b1 + c * 8 + 4);
        float bb[8] = {bl.x, bl.y, bl.z, bl.w, bh.x, bh.y, bh.z, bh.w};
        short8 o;
        #pragma unroll
        for (int k = 0; k < 8; k++)
            o[k] = (short)f2bf(fmaxf(acc[k] * rs + bb[k], 0.f));
        *(short8*)(h1 + (size_t)n * 256 + c * 8) = o;
    }
}

// ---------------- Layer-2 aggregation + fc + sigmoid: LDS e-score dedup, wave-local ----------------
// Phase 1: 64 lanes compute one edge's (src, escore) each -> LDS (exp/csr/as2 done ONCE per edge,
// was 16x redundant). Phase 2: quarter-wave per edge (mod-4 interleave for balance), 4 rows in flight.
// All LDS traffic is wave-local: no __syncthreads (waves hold different nodes with different deg).
__global__ __launch_bounds__(256) void k_l2_agg(
    const unsigned short* __restrict__ xt2, const float* __restrict__ as2,
    const float* __restrict__ ad2, const int* __restrict__ rowptr,
    const int* __restrict__ csr, const float* __restrict__ b2,
    const float* __restrict__ fcw, const float* __restrict__ fcb,
    float* __restrict__ out)
{
    __shared__ int   ssh[4][64];
    __shared__ float esh[4][64];
    int t = threadIdx.x;
    int lane = t & 63, w = t >> 6;
    int n = blockIdx.x * 4 + w;
    int beg = rowptr[n], deg = rowptr[n + 1] - beg;
    int q = lane >> 4, c = lane & 15;   // lane owns channels 4c..4c+3 (8B loads)
    float adv = ad2[n];
    const char* xb = (const char*)xt2;
    unsigned co = (unsigned)(c << 3);

    float acc[4] = {0.f, 0.f, 0.f, 0.f};
    float esum = 0.f;

    for (int j0 = 0; j0 < deg; j0 += 64) {
        int jmax = deg - j0; if (jmax > 64) jmax = 64;
        // drain prior chunk's LDS reads before overwriting (no-op on first/only chunk)
        asm volatile("s_waitcnt lgkmcnt(0)" ::: "memory");
        // phase 1: one lane per edge
        if (lane < jmax) {
            int s = csr[beg + j0 + lane];
            ssh[w][lane] = s;
            esh[w][lane] = __expf(lrelu(as2[s] + adv));
        }
        asm volatile("s_waitcnt lgkmcnt(0)" ::: "memory");
        // phase 2: quarter q takes edges k ≡ q (mod 4); 4 in flight
        int k = q;
        for (; k + 12 < jmax; k += 16) {
            int s0 = ssh[w][k],      s1 = ssh[w][k + 4];
            int s2 = ssh[w][k + 8],  s3 = ssh[w][k + 12];
            float e0 = esh[w][k],     e1 = esh[w][k + 4];
            float e2 = esh[w][k + 8], e3 = esh[w][k + 12];
            uint2 r0 = *(const uint2*)(xb + ((unsigned)(s0 << 7) + co));
            uint2 r1 = *(const uint2*)(xb + ((unsigned)(s1 << 7) + co));
            uint2 r2 = *(const uint2*)(xb + ((unsigned)(s2 << 7) + co));
            uint2 r3 = *(const uint2*)(xb + ((unsigned)(s3 << 7) + co));
            esum += (e0 + e1) + (e2 + e3);
            acc[0] += (bf2f((unsigned short)(r0.x & 0xffff)) * e0 + bf2f((unsigned short)(r1.x & 0xffff)) * e1)
                    + (bf2f((unsigned short)(r2.x & 0xffff)) * e2 + bf2f((unsigned short)(r3.x & 0xffff)) * e3);
            acc[1] += (bf2f((unsigned short)(r0.x >> 16)) * e0 + bf2f((unsigned short)(r1.x >> 16)) * e1)
                    + (bf2f((unsigned short)(r2.x >> 16)) * e2 + bf2f((unsigned short)(r3.x >> 16)) * e3);
            acc[2] += (bf2f((unsigned short)(r0.y & 0xffff)) * e0 + bf2f((unsigned short)(r1.y & 0xffff)) * e1)
                    + (bf2f((unsigned short)(r2.y & 0xffff)) * e2 + bf2f((unsigned short)(r3.y & 0xffff)) * e3);
            acc[3] += (bf2f((unsigned short)(r0.y >> 16)) * e0 + bf2f((unsigned short)(r1.y >> 16)) * e1)
                    + (bf2f((unsigned short)(r2.y >> 16)) * e2 + bf2f((unsigned short)(r3.y >> 16)) * e3);
        }
        for (; k < jmax; k += 4) {
            int s0 = ssh[w][k];
            float e0 = esh[w][k];
            uint2 r = *(const uint2*)(xb + ((unsigned)(s0 << 7) + co));
            esum += e0;
            acc[0] += bf2f((unsigned short)(r.x & 0xffff)) * e0;
            acc[1] += bf2f((unsigned short)(r.x >> 16)) * e0;
            acc[2] += bf2f((unsigned short)(r.y & 0xffff)) * e0;
            acc[3] += bf2f((unsigned short)(r.y >> 16)) * e0;
        }
    }
    #pragma unroll
    for (int k = 0; k < 4; k++) {
        acc[k] += __shfl_xor(acc[k], 16);
        acc[k] += __shfl_xor(acc[k], 32);
    }
    esum += __shfl_xor(esum, 16);
    esum += __shfl_xor(esum, 32);
    float rs = 1.f / (esum + 1e-16f);
    float4 bv = *(const float4*)(b2 + c * 4);
    float4 fv = *(const float4*)(fcw + c * 4);
    float z = fmaxf(acc[0] * rs + bv.x, 0.f) * fv.x
            + fmaxf(acc[1] * rs + bv.y, 0.f) * fv.y
            + fmaxf(acc[2] * rs + bv.z, 0.f) * fv.z
            + fmaxf(acc[3] * rs + bv.w, 0.f) * fv.w;
    #pragma unroll
    for (int off = 8; off; off >>= 1) z += __shfl_xor(z, off);
    if (lane == 0) out[n] = 1.f / (1.f + __expf(-(z + fcb[0])));
}

// ---------------- launch ----------------

extern "C" void kernel_launch(void* const* d_in, const int* in_sizes, int n_in,
                              void* d_out, int out_size, void* d_ws, size_t ws_size,
                              hipStream_t stream) {
    const float* x    = (const float*)d_in[0];
    const int*   ei   = (const int*)d_in[1];
    const float* W1   = (const float*)d_in[2];
    const float* as1w = (const float*)d_in[3];
    const float* ad1w = (const float*)d_in[4];
    const float* b1   = (const float*)d_in[5];
    const float* W2   = (const float*)d_in[6];
    const float* as2w = (const float*)d_in[7];
    const float* ad2w = (const float*)d_in[8];
    const float* b2   = (const float*)d_in[9];
    const float* fcw  = (const float*)d_in[10];
    const float* fcb  = (const float*)d_in[11];
    float* out = (float*)d_out;

    const int* src = ei;
    const int* dst = ei + EE;

    char* base = (char*)d_ws;
    size_t off = 0;
    auto alloc = [&](size_t bytes) -> void* {
        void* p = base + off;
        off = (off + bytes + 255) & ~(size_t)255;
        return p;
    };
    int*   rowptr   = (int*)alloc((NN + 1) * sizeof(int));
    int*   cnt      = (int*)alloc(NN * sizeof(int));
    int*   tmp      = (int*)alloc(NN * sizeof(int));
    int*   bsum     = (int*)alloc(SG * sizeof(int));
    int*   boff     = (int*)alloc(SG * sizeof(int));
    int*   rank     = (int*)alloc(EE * sizeof(int));
    int*   csr      = (int*)alloc(ET * sizeof(int));
    unsigned short* xt1 = (unsigned short*)alloc((size_t)NN * 256 * sizeof(unsigned short));
    unsigned short* h1  = (unsigned short*)alloc((size_t)NN * 256 * sizeof(unsigned short));
    unsigned short* w2b = (unsigned short*)alloc(64 * 256 * sizeof(unsigned short));
    float* as1      = (float*)alloc(NN * 4 * sizeof(float));
    float* ad1      = (float*)alloc(NN * 4 * sizeof(float));
    float* as2      = (float*)alloc(NN * sizeof(float));
    float* ad2      = (float*)alloc(NN * sizeof(float));
    unsigned short* xt2 = xt1;   // xt1 dead after l1_agg; reuse

    hipMemsetAsync(cnt, 0, NN * sizeof(int), stream);

    // launch A: first half of gemm1 striped with hist (+W2 convert, rank capture)
    k_gemm1_hist<<<2 * GA + (HB - GA), 256, 0, stream>>>(
        x, W1, as1w, ad1w, xt1, as1, ad1, NN, dst, cnt, rank, W2, w2b);

    k_scan1<<<SG, 256, 0, stream>>>(cnt, tmp, bsum);
    k_scan2<<<1, 256, 0, stream>>>(bsum, boff);
    k_scan3_prep<<<SG, 256, 0, stream>>>(tmp, boff, rowptr, csr);

    // launch B: second half of gemm1 striped with atomic-free scatter
    k_gemm1_scatter<<<2 * GBB + (HB - GBB), 256, 0, stream>>>(
        x, W1, as1w, ad1w, xt1, as1, ad1, NN, src, dst, rank, rowptr, csr);

    k_l1_agg<<<(NN + 3) / 4, 256, 0, stream>>>(xt1, as1, ad1, rowptr, csr, b1, h1);
    k_gemm_mfma<256, 64, 1, true, true><<<GB1, 256, 0, stream>>>(
        h1, w2b, as2w, ad2w, xt2, as2, ad2, NN);
    k_l2_agg<<<(NN + 3) / 4, 256, 0, stream>>>(xt2, as2, ad2, rowptr, csr, b2, fcw, fcb, out);
}